// Round 1
// baseline (375.959 us; speedup 1.0000x reference)
//
#include <hip/hip_runtime.h>

// Problem constants (from reference): B=4, L=10000, K=16, I=256, O=256
#define Bdim 4
#define Ldim 10000
#define Kdim 16
#define Idim 256
#define Odim 256

typedef __attribute__((ext_vector_type(8))) __bf16 bf16x8;
typedef __attribute__((ext_vector_type(4))) float f32x4;

#define TL 32          // l-values per block
#define BM 128         // = Bdim * TL rows
#define BN 128         // output cols per block
#define BK 64          // kk per staging step
#define LDA 72         // LDS row stride in bf16 (64 + 8 pad)

// C[M=40000][N=256] = A[M][4096] * W[4096][256], A gathered from x,
// W = mask reshaped (K*I, O). bf16 MFMA 16x16x32, fp32 accumulate.
__global__ __launch_bounds__(256)
void piconv_kernel(const float* __restrict__ x,
                   const int* __restrict__ idxT,
                   const float* __restrict__ mask,
                   const float* __restrict__ bias,
                   float* __restrict__ out)
{
    __shared__ __bf16 Alds[BM * LDA];   // [m][kk_local], 18.4 KB
    __shared__ __bf16 Wlds[BN * LDA];   // [n][kk_local] (transposed), 18.4 KB

    const int t  = threadIdx.x;
    const int l0 = blockIdx.x * TL;
    const int n0 = blockIdx.y * BN;

    const int lane = t & 63;
    const int wid  = t >> 6;          // 4 waves, 2x2 over (M,N)
    const int wm   = wid >> 1;
    const int wn   = wid & 1;
    const int q    = lane >> 4;       // quad 0..3
    const int r16  = lane & 15;

    f32x4 acc[4][4] = {};             // wave computes 64x64 = 4x4 of 16x16

    // A-staging assignment: 2 threads per row, 32 floats each
    const int am    = t >> 1;
    const int ahalf = t & 1;
    const int alt   = am & 31;        // l within tile
    const int abb   = am >> 5;        // batch
    const int al    = l0 + alt;
    const bool avalid = (al < Ldim);  // tail tile: invalid rows read x[b][0] (never stored)

    for (int kb = 0; kb < 64; ++kb) {
        // ---- stage A: gathered x rows, f32 -> bf16 ----
        {
            const int ksl = kb >> 2;                       // which of 16 k-slices
            const int i0  = ((kb & 3) << 6) + (ahalf << 5);
            const int idx = avalid ? idxT[al * Kdim + ksl] : 0;
            const float* src = x + (((size_t)(abb * Ldim + idx)) << 8) + i0;
#pragma unroll
            for (int j = 0; j < 4; ++j) {
                const float4 f0 = *(const float4*)(src + j * 8);
                const float4 f1 = *(const float4*)(src + j * 8 + 4);
                bf16x8 v;
                v[0] = (__bf16)f0.x; v[1] = (__bf16)f0.y;
                v[2] = (__bf16)f0.z; v[3] = (__bf16)f0.w;
                v[4] = (__bf16)f1.x; v[5] = (__bf16)f1.y;
                v[6] = (__bf16)f1.z; v[7] = (__bf16)f1.w;
                *(bf16x8*)&Alds[am * LDA + (ahalf << 5) + j * 8] = v;
            }
        }
        // ---- stage W transposed: Wlds[n][k] so b-frag reads are contiguous ----
        {
#pragma unroll
            for (int it = 0; it < 4; ++it) {
                const int pair = t + it * 256;
                const int n    = pair & 127;
                const int g    = pair >> 7;                 // 8-k group 0..7
                const float* src = mask + (((size_t)(kb * 64 + g * 8)) << 8) + n0 + n;
                bf16x8 v;
#pragma unroll
                for (int j = 0; j < 8; ++j)                 // stride-256 reads, coalesced across lanes
                    v[j] = (__bf16)src[(size_t)j << 8];
                *(bf16x8*)&Wlds[n * LDA + g * 8] = v;
            }
        }
        __syncthreads();
        // ---- compute: 2 k-steps of 16x16x32, 4x4 tiles per wave ----
#pragma unroll
        for (int ks = 0; ks < 2; ++ks) {
            bf16x8 af[4], bfr[4];
#pragma unroll
            for (int mi = 0; mi < 4; ++mi)
                af[mi] = *(bf16x8*)&Alds[(wm * 64 + mi * 16 + r16) * LDA + ks * 32 + q * 8];
#pragma unroll
            for (int ni = 0; ni < 4; ++ni)
                bfr[ni] = *(bf16x8*)&Wlds[(wn * 64 + ni * 16 + r16) * LDA + ks * 32 + q * 8];
#pragma unroll
            for (int mi = 0; mi < 4; ++mi)
#pragma unroll
                for (int ni = 0; ni < 4; ++ni)
                    acc[mi][ni] = __builtin_amdgcn_mfma_f32_16x16x32_bf16(
                        af[mi], bfr[ni], acc[mi][ni], 0, 0, 0);
        }
        __syncthreads();
    }

    // ---- epilogue: C/D layout col=lane&15, row=(lane>>4)*4+reg ----
    float bv[4];
#pragma unroll
    for (int ni = 0; ni < 4; ++ni)
        bv[ni] = bias[n0 + wn * 64 + ni * 16 + r16];
#pragma unroll
    for (int mi = 0; mi < 4; ++mi) {
        const int mrow = wm * 64 + mi * 16 + q * 4;
#pragma unroll
        for (int rr = 0; rr < 4; ++rr) {
            const int m  = mrow + rr;
            const int lt = m & 31;
            const int bb = m >> 5;
            const int l  = l0 + lt;
            if (l < Ldim) {
                float* dst = out + (((size_t)(bb * Ldim + l)) << 8) + n0 + wn * 64 + r16;
#pragma unroll
                for (int ni = 0; ni < 4; ++ni)
                    dst[ni * 16] = acc[mi][ni][rr] + bv[ni];
            }
        }
    }
}

extern "C" void kernel_launch(void* const* d_in, const int* in_sizes, int n_in,
                              void* d_out, int out_size, void* d_ws, size_t ws_size,
                              hipStream_t stream) {
    const float* x    = (const float*)d_in[0];
    const int*   idx  = (const int*)d_in[1];     // harness delivers integer inputs as int32
    const float* mask = (const float*)d_in[2];
    const float* bias = (const float*)d_in[3];
    float* out = (float*)d_out;

    dim3 grid((Ldim + TL - 1) / TL, Odim / BN, 1);   // 313 x 2
    piconv_kernel<<<grid, 256, 0, stream>>>(x, idx, mask, bias, out);
}